// Round 6
// baseline (216.874 us; speedup 1.0000x reference)
//
#include <hip/hip_runtime.h>

#define NT     25600   // B*S tokens
#define WCH    16      // chars per token
#define DIM    64
#define VOCAB  96
#define HID    128
#define FPAD   104     // per-window feature pitch in K space (100 real + 4 zero)
#define SPITCH 128     // T slot pitch (halves): 256B line-aligned rows
#define NSLOT  14      // total j-slots: 2+3+4+5
#define TROW   (NSLOT * SPITCH)   // 1792 halves per char row
#define KP     416     // GEMM K = 4*FPAD
#define TOKB   16      // tokens per block in fused kernel

typedef __attribute__((ext_vector_type(8))) _Float16 h8;
typedef __attribute__((ext_vector_type(4))) float f32x4;

__device__ __forceinline__ float tanh_fast(float m) {
  float t = fminf(fmaxf(m, -9.f), 9.f);
  float e = __builtin_amdgcn_exp2f(t * 2.885390082f);  // e^{2t}
  return 1.f - 2.f * __builtin_amdgcn_rcpf(e + 1.f);
}

// ================= prep kernel: 3 roles by blockIdx =================
// A [0,42):   T[c][slot][128] f16 (slot = b/3, cgroup = b%3), cols 100..127 = 0
// B [42,106): wprojP[128][416] f16, k = wi*104+f, pad f>=100 -> 0
// C [106,362): hw = tw0|gw0|tw1|gw1 as f16, 128*128 each
__global__ __launch_bounds__(256) void k_prep(
    const float* __restrict__ cv,
    const float* __restrict__ f2, const float* __restrict__ f3,
    const float* __restrict__ f4, const float* __restrict__ f5,
    const float* __restrict__ wproj,
    const float* __restrict__ tw0, const float* __restrict__ gw0,
    const float* __restrict__ tw1, const float* __restrict__ gw1,
    _Float16* __restrict__ T, _Float16* __restrict__ wprojP,
    _Float16* __restrict__ hw) {
  __shared__ float fS[100 * 65];
  __shared__ float cvS[32 * 65];
  const int tid = threadIdx.x;
  const int b = blockIdx.x;

  if (b < 42) {
    const int slot = b / 3, cg = b % 3;
    int wi, j;
    if (slot < 2)      { wi = 0; j = slot; }
    else if (slot < 5) { wi = 1; j = slot - 2; }
    else if (slot < 9) { wi = 2; j = slot - 5; }
    else               { wi = 3; j = slot - 9; }
    const float* filt = (wi == 0) ? f2 : (wi == 1) ? f3 : (wi == 2) ? f4 : f5;
    const int rowlen = (wi + 2) * DIM;
    for (int idx = tid; idx < 100 * DIM; idx += 256) {
      int f = idx >> 6, d = idx & 63;
      fS[f * 65 + d] = filt[f * rowlen + j * DIM + d];
    }
    for (int idx = tid; idx < 32 * DIM; idx += 256) {
      int c = idx >> 6, d = idx & 63;
      cvS[c * 65 + d] = cv[(cg * 32 + c) * DIM + d];
    }
    __syncthreads();
    for (int o = tid; o < 32 * SPITCH; o += 256) {
      int cl = o & 31, fo = o >> 5;
      float s = 0.f;
      if (fo < 100) {
#pragma unroll 8
        for (int d = 0; d < DIM; ++d) s += cvS[cl * 65 + d] * fS[fo * 65 + d];
      }
      T[(size_t)(cg * 32 + cl) * TROW + slot * SPITCH + fo] = (_Float16)s;
    }
  } else if (b < 106) {
    const int bb = b - 42;
    const int n = bb * 2 + (tid >> 7);
    const int k0 = tid & 127;
    for (int k = k0; k < KP; k += 128) {
      int wi = (k < 104) ? 0 : (k < 208) ? 1 : (k < 312) ? 2 : 3;
      int f = k - wi * FPAD;
      wprojP[n * KP + k] =
          (f < 100) ? (_Float16)wproj[n * 400 + wi * 100 + f] : (_Float16)0.f;
    }
  } else {
    const int idx = (b - 106) * 256 + tid;   // < 65536
    const int which = idx >> 14, r = idx & 16383;
    const float* src = (which == 0) ? tw0 : (which == 1) ? gw0
                     : (which == 2) ? tw1 : gw1;
    hw[idx] = (_Float16)src[r];
  }
}

// ---------------- conv helpers ----------------
template<int W>
__device__ __forceinline__ h8 rowsum(const _Float16* __restrict__ Tb,
                                     const int* __restrict__ ch, int l) {
  h8 s = *(const h8*)(Tb + ch[l]);
#pragma unroll
  for (int j = 1; j < W; ++j) s += *(const h8*)(Tb + ch[l + j] + j * SPITCH);
  return s;
}

// Two windows per thread, l-loops interleaved for MLP: ~7 independent loads
// in flight per unrolled iteration. convA layout: [slot8][token^(slot8&15)][8].
template<int WIA, int WIB>
__device__ __forceinline__ void conv_store2(const _Float16* __restrict__ T,
                                            const int* __restrict__ ch,
                                            _Float16* __restrict__ convA,
                                            int token, int octet) {
  constexpr int WA = WIA + 2, LA = 15 - WIA;
  constexpr int WB = WIB + 2, LB = 15 - WIB;
  constexpr int SBA = (WIA == 0) ? 0 : (WIA == 1) ? 2 : (WIA == 2) ? 5 : 9;
  constexpr int SBB = (WIB == 0) ? 0 : (WIB == 1) ? 2 : (WIB == 2) ? 5 : 9;
  constexpr int LMAX = (LA > LB) ? LA : LB;
  const _Float16* TbA = T + SBA * SPITCH + octet * 8;
  const _Float16* TbB = T + SBB * SPITCH + octet * 8;
  h8 mA = rowsum<WA>(TbA, ch, 0);
  h8 mB = rowsum<WB>(TbB, ch, 0);
#pragma unroll
  for (int l = 1; l < LMAX; ++l) {
    if (l < LA) mA = __builtin_elementwise_max(mA, rowsum<WA>(TbA, ch, l));
    if (l < LB) mB = __builtin_elementwise_max(mB, rowsum<WB>(TbB, ch, l));
  }
  h8 rA, rB;
#pragma unroll
  for (int i = 0; i < 8; ++i) {
    rA[i] = (_Float16)tanh_fast((float)mA[i]);
    rB[i] = (_Float16)tanh_fast((float)mB[i]);
  }
  const int sA = WIA * 13 + octet;
  const int sB = WIB * 13 + octet;
  *(h8*)(convA + sA * 128 + ((token ^ (sA & 15)) * 8)) = rA;
  *(h8*)(convA + sB * 128 + ((token ^ (sB & 15)) * 8)) = rB;
}

// ================= fused conv-lookup + MFMA head =================
// 16 tokens/block, 256 threads (4 waves). Conv items: (token, octet, half);
// half0 = windows {2,5} (83 loads), half1 = {3,4} (87 loads). 416 items.
// A-frag (16x16x32 f16): A[m=lane&15][k=quad*8+j]; D: row=quad*4+reg, col=lane&15.
__global__ __launch_bounds__(256, 4) void k_fused(
    const int* __restrict__ chars,
    const _Float16* __restrict__ T,
    const _Float16* __restrict__ wprojP,
    const _Float16* __restrict__ hw,
    const float* __restrict__ tb0, const float* __restrict__ tb1,
    const float* __restrict__ gb0, const float* __restrict__ gb1,
    float* __restrict__ out) {
  __shared__ __align__(16) _Float16 convA[52 * 128];  // 13,312 B, swizzled frag order
  __shared__ __align__(16) _Float16 xA[16 * 128];     //  4,096 B, [k>>3][row][8]
  __shared__ __align__(16) int chS[TOKB * WCH];       //  1,024 B

  const int tid = threadIdx.x;
  const int wave = tid >> 6, lane = tid & 63;
  const int m16 = lane & 15, quad = lane >> 4;
  const int tok0 = blockIdx.x * TOKB;
  const f32x4 zero = {0.f, 0.f, 0.f, 0.f};

  chS[tid] = chars[tok0 * WCH + tid] * TROW;
  __syncthreads();

  // ---- phase 1: conv via T-lookups ----
#pragma unroll
  for (int rnd = 0; rnd < 2; ++rnd) {
    const int p = tid + rnd * 256;
    if (p < 416) {
      const int token = p / 26;
      const int sub = p - token * 26;
      const int half = sub >= 13;
      const int octet = half ? sub - 13 : sub;
      int ch[WCH];
#pragma unroll
      for (int i = 0; i < WCH; ++i) ch[i] = chS[token * WCH + i];
      if (half == 0) conv_store2<0, 3>(T, ch, convA, token, octet);
      else           conv_store2<1, 2>(T, ch, convA, token, octet);
    }
  }
  __syncthreads();

  // ---- phase 2: projection GEMM xp = conv @ wprojP^T, K=416 ----
  const int hcA = wave * 16 + m16;
  const int hcB = hcA + 64;
  f32x4 xpA = zero, xpB = zero;
  for (int ks = 0; ks < 13; ++ks) {
    const int slot8 = ks * 4 + quad;
    h8 a  = *(const h8*)(convA + slot8 * 128 + ((m16 ^ (slot8 & 15)) * 8));
    h8 b0 = *(const h8*)(wprojP + (size_t)hcA * KP + ks * 32 + quad * 8);
    h8 b1 = *(const h8*)(wprojP + (size_t)hcB * KP + ks * 32 + quad * 8);
    xpA = __builtin_amdgcn_mfma_f32_16x16x32_f16(a, b0, xpA, 0, 0, 0);
    xpB = __builtin_amdgcn_mfma_f32_16x16x32_f16(a, b1, xpB, 0, 0, 0);
  }

#pragma unroll
  for (int r = 0; r < 4; ++r) {
    int row = quad * 4 + r;
    xA[(hcA >> 3) * 128 + row * 8 + (hcA & 7)]        = (_Float16)xpA[r];
    xA[((hcA + 64) >> 3) * 128 + row * 8 + (hcA & 7)] = (_Float16)xpB[r];
  }
  __syncthreads();

  // ---- highway layers ----
#pragma unroll
  for (int layer = 0; layer < 2; ++layer) {
    const _Float16* tw = hw + (layer ? 2 : 0) * HID * HID;
    const _Float16* gw = hw + (layer ? 3 : 1) * HID * HID;
    const float* tbv = layer ? tb1 : tb0;
    const float* gbv = layer ? gb1 : gb0;
    float btA = tbv[hcA], bgA = gbv[hcA];
    float btB = tbv[hcB], bgB = gbv[hcB];

    f32x4 atA = zero, atB = zero, agA = zero, agB = zero;
#pragma unroll
    for (int ks = 0; ks < 4; ++ks) {
      const int ko = ks * 32 + quad * 8;
      h8 a   = *(const h8*)(xA + (ks * 4 + quad) * 128 + m16 * 8);
      h8 bt0 = *(const h8*)(tw + (size_t)hcA * HID + ko);
      h8 bt1 = *(const h8*)(tw + (size_t)hcB * HID + ko);
      h8 bg0 = *(const h8*)(gw + (size_t)hcA * HID + ko);
      h8 bg1 = *(const h8*)(gw + (size_t)hcB * HID + ko);
      atA = __builtin_amdgcn_mfma_f32_16x16x32_f16(a, bt0, atA, 0, 0, 0);
      atB = __builtin_amdgcn_mfma_f32_16x16x32_f16(a, bt1, atB, 0, 0, 0);
      agA = __builtin_amdgcn_mfma_f32_16x16x32_f16(a, bg0, agA, 0, 0, 0);
      agB = __builtin_amdgcn_mfma_f32_16x16x32_f16(a, bg1, agB, 0, 0, 0);
    }
    __syncthreads();   // xA reads done before overwrite

#pragma unroll
    for (int r = 0; r < 4; ++r) {
      float gA = 1.f / (1.f + __builtin_amdgcn_exp2f(-(agA[r] + bgA) * 1.442695041f));
      float gB = 1.f / (1.f + __builtin_amdgcn_exp2f(-(agB[r] + bgB) * 1.442695041f));
      float tA = fmaxf(atA[r] + btA, 0.f);
      float tB = fmaxf(atB[r] + btB, 0.f);
      float xAv = gA * tA + (1.f - gA) * xpA[r];
      float xBv = gB * tB + (1.f - gB) * xpB[r];
      xpA[r] = xAv; xpB[r] = xBv;
      int row = quad * 4 + r;
      if (layer == 0) {
        xA[(hcA >> 3) * 128 + row * 8 + (hcA & 7)]        = (_Float16)xAv;
        xA[((hcA + 64) >> 3) * 128 + row * 8 + (hcA & 7)] = (_Float16)xBv;
      } else {
        out[(size_t)(tok0 + row) * HID + hcA]      = xAv;
        out[(size_t)(tok0 + row) * HID + 64 + hcA] = xBv;
      }
    }
    if (layer == 0) __syncthreads();
  }
}

extern "C" void kernel_launch(void* const* d_in, const int* in_sizes, int n_in,
                              void* d_out, int out_size, void* d_ws, size_t ws_size,
                              hipStream_t stream) {
  (void)in_sizes; (void)n_in; (void)out_size; (void)ws_size;
  const int* chars = (const int*)d_in[0];
  const float* cv  = (const float*)d_in[1];
  const float* f2  = (const float*)d_in[2];
  const float* f3  = (const float*)d_in[3];
  const float* f4  = (const float*)d_in[4];
  const float* f5  = (const float*)d_in[5];
  const float* wpj = (const float*)d_in[6];
  const float* tw0 = (const float*)d_in[7];
  const float* tb0 = (const float*)d_in[8];
  const float* tw1 = (const float*)d_in[9];
  const float* tb1 = (const float*)d_in[10];
  const float* gw0 = (const float*)d_in[11];
  const float* gb0 = (const float*)d_in[12];
  const float* gw1 = (const float*)d_in[13];
  const float* gb1 = (const float*)d_in[14];
  float* out = (float*)d_out;

  char* ws = (char*)d_ws;
  _Float16* T      = (_Float16*)ws;                       // 96*1792*2 = 344,064 B
  _Float16* wprojP = (_Float16*)(ws + 344064);            // 106,496 B
  _Float16* hw     = (_Float16*)(ws + 344064 + 106496);   // 131,072 B (total 581,632 B)

  k_prep<<<362, 256, 0, stream>>>(cv, f2, f3, f4, f5, wpj, tw0, gw0, tw1, gw1,
                                  T, wprojP, hw);
  k_fused<<<NT / TOKB, 256, 0, stream>>>(chars, T, wprojP, hw,
                                         tb0, tb1, gb0, gb1, out);
}

// Round 7
// 175.353 us; speedup vs baseline: 1.2368x; 1.2368x over previous
//
#include <hip/hip_runtime.h>

#define NT     25600   // B*S tokens
#define WCH    16      // chars per token
#define DIM    64
#define VOCAB  96
#define HID    128
#define KP     416     // GEMM K: 52 slot8-groups * 8
#define TOKB   64      // tokens per block in fused kernel
// T2 layout: [13 octets][14 slots][96 chars][8 halves]; slice = 10752 halves

typedef __attribute__((ext_vector_type(8))) _Float16 h8;
typedef __attribute__((ext_vector_type(4))) float f32x4;

__device__ __forceinline__ float tanh_fast(float m) {
  float t = fminf(fmaxf(m, -9.f), 9.f);
  float e = __builtin_amdgcn_exp2f(t * 2.885390082f);  // e^{2t}
  return 1.f - 2.f * __builtin_amdgcn_rcpf(e + 1.f);
}

// ================= prep kernel: 3 roles by blockIdx =================
// A [0,168):   T2 build; slot = b/12, char-group = b%12 (8 chars)
// B [168,232): wprojP[128][416] f16 in slot8-major k order
// C [232,488): hw = tw0|gw0|tw1|gw1 as f16, 128*128 each
__global__ __launch_bounds__(256) void k_prep(
    const float* __restrict__ cv,
    const float* __restrict__ f2, const float* __restrict__ f3,
    const float* __restrict__ f4, const float* __restrict__ f5,
    const float* __restrict__ wproj,
    const float* __restrict__ tw0, const float* __restrict__ gw0,
    const float* __restrict__ tw1, const float* __restrict__ gw1,
    _Float16* __restrict__ T2, _Float16* __restrict__ wprojP,
    _Float16* __restrict__ hw) {
  __shared__ float fS[100 * 65];
  __shared__ float cvS[8 * 65];
  const int tid = threadIdx.x;
  const int b = blockIdx.x;

  if (b < 168) {
    const int slot = b / 12, cg = b - slot * 12;
    int wi, j;
    if (slot < 2)      { wi = 0; j = slot; }
    else if (slot < 5) { wi = 1; j = slot - 2; }
    else if (slot < 9) { wi = 2; j = slot - 5; }
    else               { wi = 3; j = slot - 9; }
    const float* filt = (wi == 0) ? f2 : (wi == 1) ? f3 : (wi == 2) ? f4 : f5;
    const int rowlen = (wi + 2) * DIM;
    for (int idx = tid; idx < 100 * DIM; idx += 256) {
      int f = idx >> 6, d = idx & 63;
      fS[f * 65 + d] = filt[f * rowlen + j * DIM + d];
    }
    for (int idx = tid; idx < 8 * DIM; idx += 256) {
      int c = idx >> 6, d = idx & 63;
      cvS[c * 65 + d] = cv[(cg * 8 + c) * DIM + d];
    }
    __syncthreads();
    for (int idx = tid; idx < 8 * 104; idx += 256) {
      int cl = idx / 104, f = idx - cl * 104;
      float s = 0.f;
      if (f < 100) {
#pragma unroll 8
        for (int d = 0; d < DIM; ++d) s += cvS[cl * 65 + d] * fS[f * 65 + d];
      }
      T2[((size_t)(f >> 3) * 14 + slot) * 768 + (cg * 8 + cl) * 8 + (f & 7)] =
          (_Float16)s;
    }
  } else if (b < 232) {
    const int n = (b - 168) * 2 + (tid >> 7);
    for (int k = tid & 127; k < KP; k += 128) {
      int s8 = k >> 3;
      int wi = s8 / 13;
      int fl = (s8 - wi * 13) * 8 + (k & 7);
      wprojP[n * KP + k] =
          (fl < 100) ? (_Float16)wproj[n * 400 + wi * 100 + fl] : (_Float16)0.f;
    }
  } else {
    const int idx = (b - 232) * 256 + tid;   // < 65536
    const int which = idx >> 14, r = idx & 16383;
    const float* src = (which == 0) ? tw0 : (which == 1) ? gw0
                     : (which == 2) ? tw1 : gw1;
    hw[idx] = (_Float16)src[r];
  }
}

// ---------------- conv for one (token, window, octet) from LDS slice ----------------
// Ts: [14 slots][96 chars][8 halves]; ch[] entries pre-scaled by 8 (half offset).
template<int WI>
__device__ __forceinline__ void conv_oct(const _Float16* __restrict__ Ts,
                                         const int* __restrict__ ch,
                                         _Float16* __restrict__ convA,
                                         int token, int o) {
  constexpr int W = WI + 2, L = 15 - WI;
  constexpr int SB = (WI == 0) ? 0 : (WI == 1) ? 2 : (WI == 2) ? 5 : 9;
  h8 m;
  {
    h8 s = *(const h8*)(Ts + SB * 768 + ch[0]);
#pragma unroll
    for (int j = 1; j < W; ++j) s += *(const h8*)(Ts + (SB + j) * 768 + ch[j]);
    m = s;
  }
#pragma unroll
  for (int l = 1; l < L; ++l) {
    h8 s = *(const h8*)(Ts + SB * 768 + ch[l]);
#pragma unroll
    for (int j = 1; j < W; ++j) s += *(const h8*)(Ts + (SB + j) * 768 + ch[l + j]);
    m = __builtin_elementwise_max(m, s);
  }
  h8 r;
#pragma unroll
  for (int i = 0; i < 8; ++i) r[i] = (_Float16)tanh_fast((float)m[i]);
  const int s8 = WI * 13 + o;
  *(h8*)(convA + (s8 * 64 + (token & 48) + ((token & 15) ^ (s8 & 15))) * 8) = r;
}

// ================= fused conv (LDS-staged T) + MFMA head =================
// 64 tokens/block, 256 threads (4 waves). 13 octet rounds; per round each
// thread does one (token, window) with window = (wave + o) & 3 (wave-uniform).
// A-frag (16x16x32 f16): A[m=lane&15][k=quad*8+j]; D: row=quad*4+reg, col=lane&15.
__global__ __launch_bounds__(256) void k_fused(
    const int* __restrict__ chars,
    const _Float16* __restrict__ T2,
    const _Float16* __restrict__ wprojP,
    const _Float16* __restrict__ hw,
    const float* __restrict__ tb0, const float* __restrict__ tb1,
    const float* __restrict__ gb0, const float* __restrict__ gb1,
    float* __restrict__ out) {
  __shared__ __align__(16) char lds[78848];
  _Float16* Ts    = (_Float16*)lds;                    // 21,504 B slice
  _Float16* xA    = (_Float16*)lds;                    // 16,384 B (alias, post-conv)
  _Float16* convA = (_Float16*)(lds + 21504);          // 53,248 B
  int*      chS   = (int*)(lds + 21504 + 53248);       //  4,096 B

  const int tid = threadIdx.x;
  const int wave = tid >> 6, lane = tid & 63;
  const int m16 = lane & 15, quad = lane >> 4;
  const int tok0 = blockIdx.x * TOKB;
  const f32x4 zero = {0.f, 0.f, 0.f, 0.f};

  // stage chars transposed: chS[i*64 + t] = char * 8 (half offset in slice)
#pragma unroll
  for (int k = 0; k < 4; ++k) {
    int idx = tid + k * 256;           // idx = t*16 + i
    int t = idx >> 4, i = idx & 15;
    chS[i * 64 + t] = chars[(tok0 + t) * WCH + i] * 8;
  }
  __syncthreads();

  const int token = tid & 63;
  int ch[WCH];
#pragma unroll
  for (int i = 0; i < WCH; ++i) ch[i] = chS[i * 64 + token];

  // ---- conv: 13 octet rounds ----
  for (int o = 0; o < 13; ++o) {
    if (o) __syncthreads();            // prior round's Ts reads done
    const _Float16* src = T2 + (size_t)o * 10752;
    for (int r = tid; r < 1344; r += 256)
      *(h8*)(Ts + r * 8) = *(const h8*)(src + r * 8);
    __syncthreads();
    switch ((wave + o) & 3) {
      case 0: conv_oct<0>(Ts, ch, convA, token, o); break;
      case 1: conv_oct<1>(Ts, ch, convA, token, o); break;
      case 2: conv_oct<2>(Ts, ch, convA, token, o); break;
      default: conv_oct<3>(Ts, ch, convA, token, o); break;
    }
  }
  __syncthreads();

  // ---- projection GEMM: xp = conv @ wprojP^T, K=416, 4 m-tiles ----
  const int hcA = wave * 16 + m16;
  const int hcB = hcA + 64;
  f32x4 xp[4][2];
#pragma unroll
  for (int mt = 0; mt < 4; ++mt) { xp[mt][0] = zero; xp[mt][1] = zero; }

  for (int ks = 0; ks < 13; ++ks) {
    const int s8 = ks * 4 + quad;
    h8 b0 = *(const h8*)(wprojP + (size_t)hcA * KP + s8 * 8);
    h8 b1 = *(const h8*)(wprojP + (size_t)hcB * KP + s8 * 8);
#pragma unroll
    for (int mt = 0; mt < 4; ++mt) {
      h8 a = *(const h8*)(convA + (s8 * 64 + mt * 16 + (m16 ^ (s8 & 15))) * 8);
      xp[mt][0] = __builtin_amdgcn_mfma_f32_16x16x32_f16(a, b0, xp[mt][0], 0, 0, 0);
      xp[mt][1] = __builtin_amdgcn_mfma_f32_16x16x32_f16(a, b1, xp[mt][1], 0, 0, 0);
    }
  }

  // write x0 (f16) into xA [16 kslots][64 rows][8] (aliases Ts — safe post-barrier)
#pragma unroll
  for (int mt = 0; mt < 4; ++mt)
#pragma unroll
    for (int nt = 0; nt < 2; ++nt) {
      int col = nt * 64 + hcA;
#pragma unroll
      for (int r = 0; r < 4; ++r)
        xA[(col >> 3) * 512 + (mt * 16 + quad * 4 + r) * 8 + (col & 7)] =
            (_Float16)xp[mt][nt][r];
    }
  __syncthreads();

  // ---- highway layers ----
#pragma unroll
  for (int layer = 0; layer < 2; ++layer) {
    const _Float16* tw = hw + (layer ? 2 : 0) * HID * HID;
    const _Float16* gw = hw + (layer ? 3 : 1) * HID * HID;
    const float* tbv = layer ? tb1 : tb0;
    const float* gbv = layer ? gb1 : gb0;
    float btA = tbv[hcA], bgA = gbv[hcA];
    float btB = tbv[hcB], bgB = gbv[hcB];

    f32x4 at[4][2], ag[4][2];
#pragma unroll
    for (int mt = 0; mt < 4; ++mt) {
      at[mt][0] = zero; at[mt][1] = zero;
      ag[mt][0] = zero; ag[mt][1] = zero;
    }
#pragma unroll
    for (int ks = 0; ks < 4; ++ks) {
      const int ko = ks * 32 + quad * 8;
      h8 bt0 = *(const h8*)(tw + (size_t)hcA * HID + ko);
      h8 bt1 = *(const h8*)(tw + (size_t)hcB * HID + ko);
      h8 bg0 = *(const h8*)(gw + (size_t)hcA * HID + ko);
      h8 bg1 = *(const h8*)(gw + (size_t)hcB * HID + ko);
#pragma unroll
      for (int mt = 0; mt < 4; ++mt) {
        h8 a = *(const h8*)(xA + (ks * 4 + quad) * 512 + (mt * 16 + m16) * 8);
        at[mt][0] = __builtin_amdgcn_mfma_f32_16x16x32_f16(a, bt0, at[mt][0], 0, 0, 0);
        at[mt][1] = __builtin_amdgcn_mfma_f32_16x16x32_f16(a, bt1, at[mt][1], 0, 0, 0);
        ag[mt][0] = __builtin_amdgcn_mfma_f32_16x16x32_f16(a, bg0, ag[mt][0], 0, 0, 0);
        ag[mt][1] = __builtin_amdgcn_mfma_f32_16x16x32_f16(a, bg1, ag[mt][1], 0, 0, 0);
      }
    }
    __syncthreads();   // xA reads done before overwrite

#pragma unroll
    for (int mt = 0; mt < 4; ++mt)
#pragma unroll
      for (int nt = 0; nt < 2; ++nt) {
        float bt = nt ? btB : btA, bg = nt ? bgB : bgA;
        int col = nt * 64 + hcA;
#pragma unroll
        for (int r = 0; r < 4; ++r) {
          float g = 1.f / (1.f + __builtin_amdgcn_exp2f(
                               -(ag[mt][nt][r] + bg) * 1.442695041f));
          float tt = fmaxf(at[mt][nt][r] + bt, 0.f);
          float xn = g * tt + (1.f - g) * xp[mt][nt][r];
          xp[mt][nt][r] = xn;
          int row = mt * 16 + quad * 4 + r;
          if (layer == 0)
            xA[(col >> 3) * 512 + row * 8 + (col & 7)] = (_Float16)xn;
          else
            out[(size_t)(tok0 + row) * HID + col] = xn;
        }
      }
    if (layer == 0) __syncthreads();
  }
}

extern "C" void kernel_launch(void* const* d_in, const int* in_sizes, int n_in,
                              void* d_out, int out_size, void* d_ws, size_t ws_size,
                              hipStream_t stream) {
  (void)in_sizes; (void)n_in; (void)out_size; (void)ws_size;
  const int* chars = (const int*)d_in[0];
  const float* cv  = (const float*)d_in[1];
  const float* f2  = (const float*)d_in[2];
  const float* f3  = (const float*)d_in[3];
  const float* f4  = (const float*)d_in[4];
  const float* f5  = (const float*)d_in[5];
  const float* wpj = (const float*)d_in[6];
  const float* tw0 = (const float*)d_in[7];
  const float* tb0 = (const float*)d_in[8];
  const float* tw1 = (const float*)d_in[9];
  const float* tb1 = (const float*)d_in[10];
  const float* gw0 = (const float*)d_in[11];
  const float* gb0 = (const float*)d_in[12];
  const float* gw1 = (const float*)d_in[13];
  const float* gb1 = (const float*)d_in[14];
  float* out = (float*)d_out;

  char* ws = (char*)d_ws;
  _Float16* T2     = (_Float16*)ws;                       // 13*14*96*8*2 = 279,552 B
  _Float16* wprojP = (_Float16*)(ws + 279552);            // 106,496 B
  _Float16* hw     = (_Float16*)(ws + 279552 + 106496);   // 131,072 B (total 517,120 B)

  k_prep<<<488, 256, 0, stream>>>(cv, f2, f3, f4, f5, wpj, tw0, gw0, tw1, gw1,
                                  T2, wprojP, hw);
  k_fused<<<NT / TOKB, 256, 0, stream>>>(chars, T2, wprojP, hw,
                                         tb0, tb1, gb0, gb1, out);
}